// Round 2
// baseline (276.511 us; speedup 1.0000x reference)
//
#include <hip/hip_runtime.h>
#include <hip/hip_bf16.h>

#define B_ROWS 4096
#define D_DIM  512
#define N_ROWS 8192   // 2B
#define BM 128
#define BN 128
#define BKB 128       // K-tile in BYTES (= fp8 elements); row stride 128B, 8x16B granules
#define NBLK (N_ROWS / BM)             // 64 row-blocks
#define NPAIR (NBLK * (NBLK + 1) / 2)  // 2080 upper-tri block pairs

typedef float f32x4 __attribute__((ext_vector_type(4)));
typedef int   v4i   __attribute__((ext_vector_type(4)));
typedef int   v8i   __attribute__((ext_vector_type(8)));

// ---------------------------------------------------------------------------
// Kernel 1: per-pair prep. Block r computes norms, pos[r] (fp32 exact),
// fp8-e4m3 normalized rows Z[r], Z[r+B]; zeroes row_sum and completion ctr.
// ---------------------------------------------------------------------------
__global__ __launch_bounds__(256) void prep_kernel(
    const float* __restrict__ poly, const float* __restrict__ cemb,
    unsigned char* __restrict__ Z, float* __restrict__ row_sum,
    float* __restrict__ pos, unsigned int* __restrict__ counter)
{
    const int r = blockIdx.x;
    const int t = threadIdx.x;
    const float* prow = poly + (size_t)r * D_DIM;
    const float* crow = cemb + (size_t)r * D_DIM;

    const float2 pv = *(const float2*)(prow + 2 * t);
    const float2 cv = *(const float2*)(crow + 2 * t);

    float ssp = pv.x * pv.x + pv.y * pv.y;
    float ssc = cv.x * cv.x + cv.y * cv.y;
    float dt  = pv.x * cv.x + pv.y * cv.y;

    #pragma unroll
    for (int m = 1; m < 64; m <<= 1) {
        ssp += __shfl_xor(ssp, m);
        ssc += __shfl_xor(ssc, m);
        dt  += __shfl_xor(dt,  m);
    }
    __shared__ float red[3][4];
    const int wave = t >> 6;
    if ((t & 63) == 0) { red[0][wave] = ssp; red[1][wave] = ssc; red[2][wave] = dt; }
    __syncthreads();
    ssp = red[0][0] + red[0][1] + red[0][2] + red[0][3];
    ssc = red[1][0] + red[1][1] + red[1][2] + red[1][3];
    dt  = red[2][0] + red[2][1] + red[2][2] + red[2][3];

    const float sp = 1.0f / fmaxf(sqrtf(ssp), 1e-12f);
    const float sc = 1.0f / fmaxf(sqrtf(ssc), 1e-12f);

    unsigned char* zp = Z + (size_t)r * D_DIM;
    unsigned char* zc = Z + (size_t)(r + B_ROWS) * D_DIM;
    const int pk = __builtin_amdgcn_cvt_pk_fp8_f32(pv.x * sp, pv.y * sp, 0, false);
    const int ck = __builtin_amdgcn_cvt_pk_fp8_f32(cv.x * sc, cv.y * sc, 0, false);
    *(unsigned short*)(zp + 2 * t) = (unsigned short)(pk & 0xffff);
    *(unsigned short*)(zc + 2 * t) = (unsigned short)(ck & 0xffff);

    if (t == 0) {
        pos[r] = dt * sp * sc;
        row_sum[2 * r]     = 0.0f;
        row_sum[2 * r + 1] = 0.0f;
        if (r == 0) *counter = 0u;
    }
}

// ---------------------------------------------------------------------------
// Kernel 2: symmetric sim = Z Z^T in fp8 via mfma_scale_f32_16x16x128_f8f6f4
// with UNIT scales (E8M0 0x7F = 2^0): identical fp8 math at 2x the
// non-scaled rate; K=128/instr -> fragments are two adjacent ds_read_b128.
//
// Round-1 lesson: the dbuf version (67 KB LDS, 152 VGPR) collapsed occupancy
// to 2 blocks/CU and regressed 69->95 us (pure latency-bound regime: perf
// scaled with resident waves). This version restores the r0 residency:
// SINGLE-buffered 32 KB LDS + stage/sync/compute/sync loop (cross-block
// overlap at 4 blocks/CU does the latency hiding), and __launch_bounds__
// (256,4) to keep VGPR <= 128 (the 152-VGPR build capped waves at 8/CU).
// Epilogue / fence-free finalize unchanged (round-6 lesson: NO __threadfence).
// ---------------------------------------------------------------------------
__global__ __launch_bounds__(256, 4) void sim_kernel(
    const unsigned char* __restrict__ Z, float* __restrict__ row_sum,
    const float* __restrict__ pos, float* __restrict__ out,
    unsigned int* __restrict__ counter)
{
    __shared__ __align__(16) unsigned char As[BM * BKB];   // 16 KB
    __shared__ __align__(16) unsigned char Bs[BN * BKB];   // 16 KB
    __shared__ float rAcc[BM];
    __shared__ float cAcc[BN];
    __shared__ unsigned int lastFlag;

    // decode blockIdx.x -> (bi, bj), bi <= bj < 64; C(b) = b*(129-b)/2
    const int t0 = blockIdx.x;
    int bi = (int)((129.0f - sqrtf(16641.0f - 8.0f * (float)t0)) * 0.5f);
    #define CFN(b) ((b) * (129 - (b)) / 2)
    while (CFN(bi + 1) <= t0) ++bi;
    while (CFN(bi) > t0) --bi;
    const int bj = bi + (t0 - CFN(bi));
    #undef CFN
    const bool diag = (bi == bj);

    const int ibase = bi * BM;
    const int jbase = bj * BN;
    const int tid   = threadIdx.x;

    const int srow = tid >> 3;                 // staging row within 32-row group
    const int gchk = (tid & 7) ^ (srow & 7);   // swizzled source granule (16B)

    const int wave = tid >> 6;
    const int lane = tid & 63;
    const int wi = (wave >> 1) * 64;
    const int wj = (wave & 1) * 64;
    const int quad = lane >> 4;
    const int c    = lane & 15;

    f32x4 acc[4][4] = {};

    // LDS granule G of row R holds global granule G ^ (R&7); fragment rows
    // have R&7 == c&7. Lane needs global k = quad*32 .. +32 -> granules
    // 2*quad, 2*quad+1 at swizzled slots (they differ only in bit 0):
    const int sg0 = (((quad << 1)    ) ^ (c & 7)) * 16;
    const int sg1 = (((quad << 1) | 1) ^ (c & 7)) * 16;

    for (int k0 = 0; k0 < D_DIM; k0 += BKB) {   // 4 iterations (bytes==elems)
        #pragma unroll
        for (int it = 0; it < 4; ++it) {
            const int row = it * 32 + srow;
            const unsigned char* ga = Z + (size_t)(ibase + row) * D_DIM + k0 + gchk * 16;
            __builtin_amdgcn_global_load_lds(
                (const __attribute__((address_space(1))) void*)ga,
                (__attribute__((address_space(3))) void*)(As + it * 4096 + tid * 16),
                16, 0, 0);
        }
        if (!diag) {
            #pragma unroll
            for (int it = 0; it < 4; ++it) {
                const int row = it * 32 + srow;
                const unsigned char* gb = Z + (size_t)(jbase + row) * D_DIM + k0 + gchk * 16;
                __builtin_amdgcn_global_load_lds(
                    (const __attribute__((address_space(1))) void*)gb,
                    (__attribute__((address_space(3))) void*)(Bs + it * 4096 + tid * 16),
                    16, 0, 0);
            }
        }
        __syncthreads();

        const unsigned char* bb = diag ? As : Bs;

        v8i bfr[4];
        #pragma unroll
        for (int tj = 0; tj < 4; ++tj) {
            const unsigned char* base = bb + (wj + tj * 16 + c) * BKB;
            const v4i lo = *(const v4i*)(base + sg0);
            const v4i hi = *(const v4i*)(base + sg1);
            bfr[tj] = __builtin_shufflevector(lo, hi, 0, 1, 2, 3, 4, 5, 6, 7);
        }
        #pragma unroll
        for (int ti = 0; ti < 4; ++ti) {
            const unsigned char* base = As + (wi + ti * 16 + c) * BKB;
            const v4i lo = *(const v4i*)(base + sg0);
            const v4i hi = *(const v4i*)(base + sg1);
            const v8i afr = __builtin_shufflevector(lo, hi, 0, 1, 2, 3, 4, 5, 6, 7);
            #pragma unroll
            for (int tj = 0; tj < 4; ++tj)
                acc[ti][tj] = __builtin_amdgcn_mfma_scale_f32_16x16x128_f8f6f4(
                    afr, bfr[tj], acc[ti][tj],
                    0, 0,                 // cbsz / blgp: fp8 e4m3 both
                    0, 0x7f7f7f7f,        // opsel_a, scale_a = 1.0 (E8M0 127)
                    0, 0x7f7f7f7f);       // opsel_b, scale_b = 1.0
        }
        __syncthreads();
    }

    // ---- Epilogue: strict-upper exp(sim/T), pre-reduced in LDS ----
    if (tid < BM) { rAcc[tid] = 0.0f; cAcc[tid] = 0.0f; }
    __syncthreads();

    const float K2 = 2.885390081777927f;  // 2*log2(e) = 1/(T*ln2)
    float col[4] = {0.0f, 0.0f, 0.0f, 0.0f};
    #pragma unroll
    for (int ti = 0; ti < 4; ++ti) {
        const int li = wi + ti * 16 + quad * 4;
        #pragma unroll
        for (int r = 0; r < 4; ++r) {
            const int gi = ibase + li + r;
            float v = 0.0f;
            #pragma unroll
            for (int tj = 0; tj < 4; ++tj) {
                const int gj = jbase + wj + tj * 16 + c;
                const float e = (gj > gi) ? exp2f(K2 * acc[ti][tj][r]) : 0.0f;
                v += e;
                col[tj] += e;
            }
            v += __shfl_xor(v, 1);
            v += __shfl_xor(v, 2);
            v += __shfl_xor(v, 4);
            v += __shfl_xor(v, 8);
            if (c == 0)
                atomicAdd(&rAcc[li + r], v);
        }
    }
    #pragma unroll
    for (int tj = 0; tj < 4; ++tj) {
        float w = col[tj];
        w += __shfl_xor(w, 16);
        w += __shfl_xor(w, 32);
        if (quad == 0)
            atomicAdd(&cAcc[wj + tj * 16 + c], w);
    }
    __syncthreads();

    if (tid < BM)
        atomicAdd(&row_sum[ibase + tid], rAcc[tid]);
    else
        atomicAdd(&row_sum[jbase + tid - BM], cAcc[tid - BM]);

    // ---- Completion count; last block computes the loss (fence-free) ----
    __syncthreads();   // barrier implies vmcnt(0): this block's atomics issued
    if (tid == 0) {
        unsigned int old = __hip_atomic_fetch_add(
            counter, 1u, __ATOMIC_RELAXED, __HIP_MEMORY_SCOPE_AGENT);
        lastFlag = (old == NPAIR - 1) ? 1u : 0u;
    }
    __syncthreads();
    if (lastFlag) {
        float accL = 0.0f, accP = 0.0f;
        for (int i = tid; i < N_ROWS; i += 256) {
            const float rs = __hip_atomic_load(
                &row_sum[i], __ATOMIC_RELAXED, __HIP_MEMORY_SCOPE_AGENT);
            accL += __logf(rs);
        }
        for (int r = tid; r < B_ROWS; r += 256)
            accP += pos[r];
        #pragma unroll
        for (int m = 1; m < 64; m <<= 1) {
            accL += __shfl_xor(accL, m);
            accP += __shfl_xor(accP, m);
        }
        if (lane == 0) { rAcc[wave] = accL; cAcc[wave] = accP; }
        __syncthreads();
        if (tid == 0) {
            float L = 0.0f, P = 0.0f;
            #pragma unroll
            for (int w = 0; w < 4; ++w) { L += rAcc[w]; P += cAcc[w]; }
            out[0] = (L - 4.0f * P) / (float)N_ROWS;
        }
    }
}

extern "C" void kernel_launch(void* const* d_in, const int* in_sizes, int n_in,
                              void* d_out, int out_size, void* d_ws, size_t ws_size,
                              hipStream_t stream) {
    const float* poly = (const float*)d_in[0];
    const float* cemb = (const float*)d_in[1];

    unsigned char* Z       = (unsigned char*)d_ws;
    float*         row_sum = (float*)((char*)d_ws + (size_t)N_ROWS * D_DIM);
    float*         pos     = row_sum + N_ROWS;
    unsigned int*  counter = (unsigned int*)(pos + B_ROWS);
    float*         out     = (float*)d_out;

    prep_kernel<<<B_ROWS, 256, 0, stream>>>(poly, cemb, Z, row_sum, pos, counter);
    sim_kernel<<<NPAIR, 256, 0, stream>>>(Z, row_sum, pos, out, counter);
}

// Round 3
// 205.068 us; speedup vs baseline: 1.3484x; 1.3484x over previous
//
#include <hip/hip_runtime.h>
#include <hip/hip_bf16.h>

#define B_ROWS 4096
#define D_DIM  512
#define N_ROWS 8192   // 2B
#define BM 128
#define BN 128
#define BKB 128       // K-tile in BYTES (= fp8 elements); row stride 128B, 8x16B granules
#define NBLK (N_ROWS / BM)             // 64 row-blocks
#define NPAIR (NBLK * (NBLK + 1) / 2)  // 2080 upper-tri block pairs

typedef float f32x4 __attribute__((ext_vector_type(4)));
typedef int   v4i   __attribute__((ext_vector_type(4)));
typedef int   v8i   __attribute__((ext_vector_type(8)));

// ---------------------------------------------------------------------------
// Kernel 1: per-pair prep. Block r computes norms, pos[r] (fp32 exact),
// fp8-e4m3 normalized rows Z[r], Z[r+B]; zeroes row_sum and completion ctr.
// ---------------------------------------------------------------------------
__global__ __launch_bounds__(256) void prep_kernel(
    const float* __restrict__ poly, const float* __restrict__ cemb,
    unsigned char* __restrict__ Z, float* __restrict__ row_sum,
    float* __restrict__ pos, unsigned int* __restrict__ counter)
{
    const int r = blockIdx.x;
    const int t = threadIdx.x;
    const float* prow = poly + (size_t)r * D_DIM;
    const float* crow = cemb + (size_t)r * D_DIM;

    const float2 pv = *(const float2*)(prow + 2 * t);
    const float2 cv = *(const float2*)(crow + 2 * t);

    float ssp = pv.x * pv.x + pv.y * pv.y;
    float ssc = cv.x * cv.x + cv.y * cv.y;
    float dt  = pv.x * cv.x + pv.y * cv.y;

    #pragma unroll
    for (int m = 1; m < 64; m <<= 1) {
        ssp += __shfl_xor(ssp, m);
        ssc += __shfl_xor(ssc, m);
        dt  += __shfl_xor(dt,  m);
    }
    __shared__ float red[3][4];
    const int wave = t >> 6;
    if ((t & 63) == 0) { red[0][wave] = ssp; red[1][wave] = ssc; red[2][wave] = dt; }
    __syncthreads();
    ssp = red[0][0] + red[0][1] + red[0][2] + red[0][3];
    ssc = red[1][0] + red[1][1] + red[1][2] + red[1][3];
    dt  = red[2][0] + red[2][1] + red[2][2] + red[2][3];

    const float sp = 1.0f / fmaxf(sqrtf(ssp), 1e-12f);
    const float sc = 1.0f / fmaxf(sqrtf(ssc), 1e-12f);

    unsigned char* zp = Z + (size_t)r * D_DIM;
    unsigned char* zc = Z + (size_t)(r + B_ROWS) * D_DIM;
    const int pk = __builtin_amdgcn_cvt_pk_fp8_f32(pv.x * sp, pv.y * sp, 0, false);
    const int ck = __builtin_amdgcn_cvt_pk_fp8_f32(cv.x * sc, cv.y * sc, 0, false);
    *(unsigned short*)(zp + 2 * t) = (unsigned short)(pk & 0xffff);
    *(unsigned short*)(zc + 2 * t) = (unsigned short)(ck & 0xffff);

    if (t == 0) {
        pos[r] = dt * sp * sc;
        row_sum[2 * r]     = 0.0f;
        row_sum[2 * r + 1] = 0.0f;
        if (r == 0) *counter = 0u;
    }
}

// ---------------------------------------------------------------------------
// Kernel 2: symmetric sim = Z Z^T via mfma_scale_f32_16x16x128_f8f6f4 with
// UNIT scales (identical fp8 math at 2x the non-scaled rate).
//
// Round-1 lesson: dbuf + 152 VGPR -> 8 waves/CU -> latency-bound regress.
// Round-2 lesson: forcing a 4-wave block under a 128-reg cap SPILLS (the
// 64x64-per-wave shape needs acc64+bfr32+afr8 ~ 104+ live): VGPR_Count=64,
// 500 MB scratch FETCH, 237 us. Don't fight the allocator -- shrink the
// per-wave tile instead.
//
// This version: 8 waves (512 thr), per-wave 64x32 output: acc[4][2]=32,
// bfr[2]=16, afr=8 -> ~90-110 live, fits the 128 cap naturally. 16 waves/CU
// (2 blocks) at r0 residency with half the MFMA issues and 3/4 the LDS
// reads. Single-buffered 32 KB LDS; stage/sync/compute/sync; cross-block
// overlap hides latency. Epilogue / fence-free finalize as verified.
// ---------------------------------------------------------------------------
__global__ __launch_bounds__(512, 4) void sim_kernel(
    const unsigned char* __restrict__ Z, float* __restrict__ row_sum,
    const float* __restrict__ pos, float* __restrict__ out,
    unsigned int* __restrict__ counter)
{
    __shared__ __align__(16) unsigned char As[BM * BKB];   // 16 KB
    __shared__ __align__(16) unsigned char Bs[BN * BKB];   // 16 KB
    __shared__ float rAcc[BM];
    __shared__ float cAcc[BN];
    __shared__ unsigned int lastFlag;

    // decode blockIdx.x -> (bi, bj), bi <= bj < 64; C(b) = b*(129-b)/2
    const int t0 = blockIdx.x;
    int bi = (int)((129.0f - sqrtf(16641.0f - 8.0f * (float)t0)) * 0.5f);
    #define CFN(b) ((b) * (129 - (b)) / 2)
    while (CFN(bi + 1) <= t0) ++bi;
    while (CFN(bi) > t0) --bi;
    const int bj = bi + (t0 - CFN(bi));
    #undef CFN
    const bool diag = (bi == bj);

    const int ibase = bi * BM;
    const int jbase = bj * BN;
    const int tid   = threadIdx.x;

    const int srow = tid >> 3;                 // staging row (0..63) within 64-row group
    const int gchk = (tid & 7) ^ (srow & 7);   // swizzled source granule (16B)

    const int wave = tid >> 6;                 // 0..7
    const int lane = tid & 63;
    const int wi = (wave >> 2) * 64;           // 2 row groups of 64
    const int wj = (wave & 3) * 32;            // 4 col groups of 32
    const int quad = lane >> 4;
    const int c    = lane & 15;

    f32x4 acc[4][2] = {};

    // LDS granule G of row R holds global granule G ^ (R&7); fragment rows
    // have R&7 == c&7. Lane needs global k = quad*32 .. +32 -> granules
    // 2*quad, 2*quad+1 at swizzled slots:
    const int sg0 = (((quad << 1)    ) ^ (c & 7)) * 16;
    const int sg1 = (((quad << 1) | 1) ^ (c & 7)) * 16;

    for (int k0 = 0; k0 < D_DIM; k0 += BKB) {   // 4 iterations (bytes==elems)
        #pragma unroll
        for (int it = 0; it < 2; ++it) {        // 512 thr x 16B x 2 = 16 KB
            const int row = it * 64 + srow;
            const unsigned char* ga = Z + (size_t)(ibase + row) * D_DIM + k0 + gchk * 16;
            __builtin_amdgcn_global_load_lds(
                (const __attribute__((address_space(1))) void*)ga,
                (__attribute__((address_space(3))) void*)(As + it * 8192 + tid * 16),
                16, 0, 0);
        }
        if (!diag) {
            #pragma unroll
            for (int it = 0; it < 2; ++it) {
                const int row = it * 64 + srow;
                const unsigned char* gb = Z + (size_t)(jbase + row) * D_DIM + k0 + gchk * 16;
                __builtin_amdgcn_global_load_lds(
                    (const __attribute__((address_space(1))) void*)gb,
                    (__attribute__((address_space(3))) void*)(Bs + it * 8192 + tid * 16),
                    16, 0, 0);
            }
        }
        __syncthreads();

        const unsigned char* bb = diag ? As : Bs;

        v8i bfr[2];
        #pragma unroll
        for (int tj = 0; tj < 2; ++tj) {
            const unsigned char* base = bb + (wj + tj * 16 + c) * BKB;
            const v4i lo = *(const v4i*)(base + sg0);
            const v4i hi = *(const v4i*)(base + sg1);
            bfr[tj] = __builtin_shufflevector(lo, hi, 0, 1, 2, 3, 4, 5, 6, 7);
        }
        #pragma unroll
        for (int ti = 0; ti < 4; ++ti) {
            const unsigned char* base = As + (wi + ti * 16 + c) * BKB;
            const v4i lo = *(const v4i*)(base + sg0);
            const v4i hi = *(const v4i*)(base + sg1);
            const v8i afr = __builtin_shufflevector(lo, hi, 0, 1, 2, 3, 4, 5, 6, 7);
            #pragma unroll
            for (int tj = 0; tj < 2; ++tj)
                acc[ti][tj] = __builtin_amdgcn_mfma_scale_f32_16x16x128_f8f6f4(
                    afr, bfr[tj], acc[ti][tj],
                    0, 0,                 // cbsz / blgp: fp8 e4m3 both
                    0, 0x7f7f7f7f,        // opsel_a, scale_a = 1.0 (E8M0 127)
                    0, 0x7f7f7f7f);       // opsel_b, scale_b = 1.0
        }
        __syncthreads();
    }

    // ---- Epilogue: strict-upper exp(sim/T), pre-reduced in LDS ----
    if (tid < BM) { rAcc[tid] = 0.0f; cAcc[tid] = 0.0f; }
    __syncthreads();

    const float K2 = 2.885390081777927f;  // 2*log2(e) = 1/(T*ln2)
    float col[2] = {0.0f, 0.0f};
    #pragma unroll
    for (int ti = 0; ti < 4; ++ti) {
        const int li = wi + ti * 16 + quad * 4;
        #pragma unroll
        for (int r = 0; r < 4; ++r) {
            const int gi = ibase + li + r;
            float v = 0.0f;
            #pragma unroll
            for (int tj = 0; tj < 2; ++tj) {
                const int gj = jbase + wj + tj * 16 + c;
                const float e = (gj > gi) ? exp2f(K2 * acc[ti][tj][r]) : 0.0f;
                v += e;
                col[tj] += e;
            }
            v += __shfl_xor(v, 1);
            v += __shfl_xor(v, 2);
            v += __shfl_xor(v, 4);
            v += __shfl_xor(v, 8);
            if (c == 0)
                atomicAdd(&rAcc[li + r], v);
        }
    }
    #pragma unroll
    for (int tj = 0; tj < 2; ++tj) {
        float w = col[tj];
        w += __shfl_xor(w, 16);
        w += __shfl_xor(w, 32);
        if (quad == 0)
            atomicAdd(&cAcc[wj + tj * 16 + c], w);
    }
    __syncthreads();

    if (tid < BM)
        atomicAdd(&row_sum[ibase + tid], rAcc[tid]);
    else if (tid < 2 * BM)
        atomicAdd(&row_sum[jbase + tid - BM], cAcc[tid - BM]);

    // ---- Completion count; last block computes the loss (fence-free) ----
    __syncthreads();   // barrier implies vmcnt(0): this block's atomics issued
    if (tid == 0) {
        unsigned int old = __hip_atomic_fetch_add(
            counter, 1u, __ATOMIC_RELAXED, __HIP_MEMORY_SCOPE_AGENT);
        lastFlag = (old == NPAIR - 1) ? 1u : 0u;
    }
    __syncthreads();
    if (lastFlag) {
        float accL = 0.0f, accP = 0.0f;
        for (int i = tid; i < N_ROWS; i += 512) {
            const float rs = __hip_atomic_load(
                &row_sum[i], __ATOMIC_RELAXED, __HIP_MEMORY_SCOPE_AGENT);
            accL += __logf(rs);
        }
        for (int r = tid; r < B_ROWS; r += 512)
            accP += pos[r];
        #pragma unroll
        for (int m = 1; m < 64; m <<= 1) {
            accL += __shfl_xor(accL, m);
            accP += __shfl_xor(accP, m);
        }
        if (lane == 0) { rAcc[wave] = accL; cAcc[wave] = accP; }
        __syncthreads();
        if (tid == 0) {
            float L = 0.0f, P = 0.0f;
            #pragma unroll
            for (int w = 0; w < 8; ++w) { L += rAcc[w]; P += cAcc[w]; }
            out[0] = (L - 4.0f * P) / (float)N_ROWS;
        }
    }
}

extern "C" void kernel_launch(void* const* d_in, const int* in_sizes, int n_in,
                              void* d_out, int out_size, void* d_ws, size_t ws_size,
                              hipStream_t stream) {
    const float* poly = (const float*)d_in[0];
    const float* cemb = (const float*)d_in[1];

    unsigned char* Z       = (unsigned char*)d_ws;
    float*         row_sum = (float*)((char*)d_ws + (size_t)N_ROWS * D_DIM);
    float*         pos     = row_sum + N_ROWS;
    unsigned int*  counter = (unsigned int*)(pos + B_ROWS);
    float*         out     = (float*)d_out;

    prep_kernel<<<B_ROWS, 256, 0, stream>>>(poly, cemb, Z, row_sum, pos, counter);
    sim_kernel<<<NPAIR, 512, 0, stream>>>(Z, row_sum, pos, out, counter);
}

// Round 4
// 157.336 us; speedup vs baseline: 1.7575x; 1.3034x over previous
//
#include <hip/hip_runtime.h>
#include <hip/hip_bf16.h>

#define B_ROWS 4096
#define D_DIM  512
#define N_ROWS 8192   // 2B
#define BM 128
#define BN 128
#define BKB 128       // K-tile in BYTES (= fp8 elements); row stride 128B, 8x16B granules
#define NBLK (N_ROWS / BM)             // 64 row-blocks
#define NPAIR (NBLK * (NBLK + 1) / 2)  // 2080 upper-tri block pairs

typedef float f32x4 __attribute__((ext_vector_type(4)));
typedef int   v4i   __attribute__((ext_vector_type(4)));
typedef int   v8i   __attribute__((ext_vector_type(8)));

// ---------------------------------------------------------------------------
// Kernel 1: per-pair prep. Block r computes norms, pos[r] (fp32 exact),
// fp8-e4m3 normalized rows Z[r], Z[r+B]; zeroes row_sum and completion ctr.
// ---------------------------------------------------------------------------
__global__ __launch_bounds__(256) void prep_kernel(
    const float* __restrict__ poly, const float* __restrict__ cemb,
    unsigned char* __restrict__ Z, float* __restrict__ row_sum,
    float* __restrict__ pos, unsigned int* __restrict__ counter)
{
    const int r = blockIdx.x;
    const int t = threadIdx.x;
    const float* prow = poly + (size_t)r * D_DIM;
    const float* crow = cemb + (size_t)r * D_DIM;

    const float2 pv = *(const float2*)(prow + 2 * t);
    const float2 cv = *(const float2*)(crow + 2 * t);

    float ssp = pv.x * pv.x + pv.y * pv.y;
    float ssc = cv.x * cv.x + cv.y * cv.y;
    float dt  = pv.x * cv.x + pv.y * cv.y;

    #pragma unroll
    for (int m = 1; m < 64; m <<= 1) {
        ssp += __shfl_xor(ssp, m);
        ssc += __shfl_xor(ssc, m);
        dt  += __shfl_xor(dt,  m);
    }
    __shared__ float red[3][4];
    const int wave = t >> 6;
    if ((t & 63) == 0) { red[0][wave] = ssp; red[1][wave] = ssc; red[2][wave] = dt; }
    __syncthreads();
    ssp = red[0][0] + red[0][1] + red[0][2] + red[0][3];
    ssc = red[1][0] + red[1][1] + red[1][2] + red[1][3];
    dt  = red[2][0] + red[2][1] + red[2][2] + red[2][3];

    const float sp = 1.0f / fmaxf(sqrtf(ssp), 1e-12f);
    const float sc = 1.0f / fmaxf(sqrtf(ssc), 1e-12f);

    unsigned char* zp = Z + (size_t)r * D_DIM;
    unsigned char* zc = Z + (size_t)(r + B_ROWS) * D_DIM;
    const int pk = __builtin_amdgcn_cvt_pk_fp8_f32(pv.x * sp, pv.y * sp, 0, false);
    const int ck = __builtin_amdgcn_cvt_pk_fp8_f32(cv.x * sc, cv.y * sc, 0, false);
    *(unsigned short*)(zp + 2 * t) = (unsigned short)(pk & 0xffff);
    *(unsigned short*)(zc + 2 * t) = (unsigned short)(ck & 0xffff);

    if (t == 0) {
        pos[r] = dt * sp * sc;
        row_sum[2 * r]     = 0.0f;
        row_sum[2 * r + 1] = 0.0f;
        if (r == 0) *counter = 0u;
    }
}

// ---------------------------------------------------------------------------
// Kernel 2: symmetric sim = Z Z^T via mfma_scale_f32_16x16x128_f8f6f4 with
// UNIT scales (E8M0 0x7F = 2^0): identical fp8 math at 2x the non-scaled
// rate; K=128/instr -> fragments are two adjacent ds_read_b128 (verified
// absmax 0.0 in rounds 1-3).
//
// Occupancy lessons:
//   r1: dbuf 67 KB LDS -> 2 blocks/CU -> 94.8 us (latency-bound).
//   r2/r3: ANY __launch_bounds__ min-waves cap with this inner loop makes
//          the allocator spill to scratch (285-500 MB WRITE, VGPR=64).
//   r0's real budget was 84 arch + 64 AGPR ~ 148/wave = 3 waves/SIMD,
//   the SAME class as the natural scaled build (152). So: round-0 skeleton
//   (single-buffer 32 KB LDS, stage/sync/compute/sync, 4 waves of 64x64,
//   NO occupancy bound) + scaled-MFMA inner loop = r0 residency with half
//   the MFMA pipe time and ~40% of the LDS-read cycles.
// Epilogue / fence-free finalize byte-identical to round 0.
// ---------------------------------------------------------------------------
__global__ __launch_bounds__(256) void sim_kernel(
    const unsigned char* __restrict__ Z, float* __restrict__ row_sum,
    const float* __restrict__ pos, float* __restrict__ out,
    unsigned int* __restrict__ counter)
{
    __shared__ __align__(16) unsigned char As[BM * BKB];   // 16 KB
    __shared__ __align__(16) unsigned char Bs[BN * BKB];   // 16 KB
    __shared__ float rAcc[BM];
    __shared__ float cAcc[BN];
    __shared__ unsigned int lastFlag;

    // decode blockIdx.x -> (bi, bj), bi <= bj < 64; C(b) = b*(129-b)/2
    const int t0 = blockIdx.x;
    int bi = (int)((129.0f - sqrtf(16641.0f - 8.0f * (float)t0)) * 0.5f);
    #define CFN(b) ((b) * (129 - (b)) / 2)
    while (CFN(bi + 1) <= t0) ++bi;
    while (CFN(bi) > t0) --bi;
    const int bj = bi + (t0 - CFN(bi));
    #undef CFN
    const bool diag = (bi == bj);

    const int ibase = bi * BM;
    const int jbase = bj * BN;
    const int tid   = threadIdx.x;

    const int srow = tid >> 3;                 // staging row within 32-row group
    const int gchk = (tid & 7) ^ (srow & 7);   // swizzled source granule (16B)

    const int wave = tid >> 6;
    const int lane = tid & 63;
    const int wi = (wave >> 1) * 64;
    const int wj = (wave & 1) * 64;
    const int quad = lane >> 4;
    const int c    = lane & 15;

    f32x4 acc[4][4] = {};

    // LDS granule G of row R holds global granule G ^ (R&7); fragment rows
    // have R&7 == c&7. Lane needs global k = quad*32 .. +32 -> granules
    // 2*quad, 2*quad+1 at swizzled slots:
    const int sg0 = (((quad << 1)    ) ^ (c & 7)) * 16;
    const int sg1 = (((quad << 1) | 1) ^ (c & 7)) * 16;

    for (int k0 = 0; k0 < D_DIM; k0 += BKB) {   // 4 iterations (bytes==elems)
        #pragma unroll
        for (int it = 0; it < 4; ++it) {
            const int row = it * 32 + srow;
            const unsigned char* ga = Z + (size_t)(ibase + row) * D_DIM + k0 + gchk * 16;
            __builtin_amdgcn_global_load_lds(
                (const __attribute__((address_space(1))) void*)ga,
                (__attribute__((address_space(3))) void*)(As + it * 4096 + tid * 16),
                16, 0, 0);
        }
        if (!diag) {
            #pragma unroll
            for (int it = 0; it < 4; ++it) {
                const int row = it * 32 + srow;
                const unsigned char* gb = Z + (size_t)(jbase + row) * D_DIM + k0 + gchk * 16;
                __builtin_amdgcn_global_load_lds(
                    (const __attribute__((address_space(1))) void*)gb,
                    (__attribute__((address_space(3))) void*)(Bs + it * 4096 + tid * 16),
                    16, 0, 0);
            }
        }
        __syncthreads();

        const unsigned char* bb = diag ? As : Bs;

        v8i bfr[4];
        #pragma unroll
        for (int tj = 0; tj < 4; ++tj) {
            const unsigned char* base = bb + (wj + tj * 16 + c) * BKB;
            const v4i lo = *(const v4i*)(base + sg0);
            const v4i hi = *(const v4i*)(base + sg1);
            bfr[tj] = __builtin_shufflevector(lo, hi, 0, 1, 2, 3, 4, 5, 6, 7);
        }
        #pragma unroll
        for (int ti = 0; ti < 4; ++ti) {
            const unsigned char* base = As + (wi + ti * 16 + c) * BKB;
            const v4i lo = *(const v4i*)(base + sg0);
            const v4i hi = *(const v4i*)(base + sg1);
            const v8i afr = __builtin_shufflevector(lo, hi, 0, 1, 2, 3, 4, 5, 6, 7);
            #pragma unroll
            for (int tj = 0; tj < 4; ++tj)
                acc[ti][tj] = __builtin_amdgcn_mfma_scale_f32_16x16x128_f8f6f4(
                    afr, bfr[tj], acc[ti][tj],
                    0, 0,                 // cbsz / blgp: fp8 e4m3 both
                    0, 0x7f7f7f7f,        // opsel_a, scale_a = 1.0 (E8M0 127)
                    0, 0x7f7f7f7f);       // opsel_b, scale_b = 1.0
        }
        __syncthreads();
    }

    // ---- Epilogue: strict-upper exp(sim/T), pre-reduced in LDS ----
    if (tid < BM) { rAcc[tid] = 0.0f; cAcc[tid] = 0.0f; }
    __syncthreads();

    const float K2 = 2.885390081777927f;  // 2*log2(e) = 1/(T*ln2)
    float col[4] = {0.0f, 0.0f, 0.0f, 0.0f};
    #pragma unroll
    for (int ti = 0; ti < 4; ++ti) {
        const int li = wi + ti * 16 + quad * 4;
        #pragma unroll
        for (int r = 0; r < 4; ++r) {
            const int gi = ibase + li + r;
            float v = 0.0f;
            #pragma unroll
            for (int tj = 0; tj < 4; ++tj) {
                const int gj = jbase + wj + tj * 16 + c;
                const float e = (gj > gi) ? exp2f(K2 * acc[ti][tj][r]) : 0.0f;
                v += e;
                col[tj] += e;
            }
            v += __shfl_xor(v, 1);
            v += __shfl_xor(v, 2);
            v += __shfl_xor(v, 4);
            v += __shfl_xor(v, 8);
            if (c == 0)
                atomicAdd(&rAcc[li + r], v);
        }
    }
    #pragma unroll
    for (int tj = 0; tj < 4; ++tj) {
        float w = col[tj];
        w += __shfl_xor(w, 16);
        w += __shfl_xor(w, 32);
        if (quad == 0)
            atomicAdd(&cAcc[wj + tj * 16 + c], w);
    }
    __syncthreads();

    if (tid < BM)
        atomicAdd(&row_sum[ibase + tid], rAcc[tid]);
    else
        atomicAdd(&row_sum[jbase + tid - BM], cAcc[tid - BM]);

    // ---- Completion count; last block computes the loss (fence-free) ----
    __syncthreads();   // barrier implies vmcnt(0): this block's atomics issued
    if (tid == 0) {
        unsigned int old = __hip_atomic_fetch_add(
            counter, 1u, __ATOMIC_RELAXED, __HIP_MEMORY_SCOPE_AGENT);
        lastFlag = (old == NPAIR - 1) ? 1u : 0u;
    }
    __syncthreads();
    if (lastFlag) {
        float accL = 0.0f, accP = 0.0f;
        for (int i = tid; i < N_ROWS; i += 256) {
            const float rs = __hip_atomic_load(
                &row_sum[i], __ATOMIC_RELAXED, __HIP_MEMORY_SCOPE_AGENT);
            accL += __logf(rs);
        }
        for (int r = tid; r < B_ROWS; r += 256)
            accP += pos[r];
        #pragma unroll
        for (int m = 1; m < 64; m <<= 1) {
            accL += __shfl_xor(accL, m);
            accP += __shfl_xor(accP, m);
        }
        if (lane == 0) { rAcc[wave] = accL; cAcc[wave] = accP; }
        __syncthreads();
        if (tid == 0) {
            float L = 0.0f, P = 0.0f;
            #pragma unroll
            for (int w = 0; w < 4; ++w) { L += rAcc[w]; P += cAcc[w]; }
            out[0] = (L - 4.0f * P) / (float)N_ROWS;
        }
    }
}

extern "C" void kernel_launch(void* const* d_in, const int* in_sizes, int n_in,
                              void* d_out, int out_size, void* d_ws, size_t ws_size,
                              hipStream_t stream) {
    const float* poly = (const float*)d_in[0];
    const float* cemb = (const float*)d_in[1];

    unsigned char* Z       = (unsigned char*)d_ws;
    float*         row_sum = (float*)((char*)d_ws + (size_t)N_ROWS * D_DIM);
    float*         pos     = row_sum + N_ROWS;
    unsigned int*  counter = (unsigned int*)(pos + B_ROWS);
    float*         out     = (float*)d_out;

    prep_kernel<<<B_ROWS, 256, 0, stream>>>(poly, cemb, Z, row_sum, pos, counter);
    sim_kernel<<<NPAIR, 256, 0, stream>>>(Z, row_sum, pos, out, counter);
}

// Round 5
// 155.421 us; speedup vs baseline: 1.7791x; 1.0123x over previous
//
#include <hip/hip_runtime.h>
#include <hip/hip_bf16.h>

#define B_ROWS 4096
#define D_DIM  512
#define N_ROWS 8192   // 2B
#define BM 128
#define BN 128
#define BKB 128       // K-step in BYTES (= fp8 elements) per loop iteration
#define NBLK (N_ROWS / BM)             // 64 row-blocks
#define NPAIR (NBLK * (NBLK + 1) / 2)  // 2080 upper-tri block pairs

typedef float f32x4 __attribute__((ext_vector_type(4)));
typedef int   v4i   __attribute__((ext_vector_type(4)));
typedef int   v8i   __attribute__((ext_vector_type(8)));

// ---------------------------------------------------------------------------
// Kernel 1: per-pair prep. Block r computes norms, pos[r] (fp32 exact),
// fp8-e4m3 normalized rows Z[r], Z[r+B]; zeroes row_sum and completion ctr.
// ---------------------------------------------------------------------------
__global__ __launch_bounds__(256) void prep_kernel(
    const float* __restrict__ poly, const float* __restrict__ cemb,
    unsigned char* __restrict__ Z, float* __restrict__ row_sum,
    float* __restrict__ pos, unsigned int* __restrict__ counter)
{
    const int r = blockIdx.x;
    const int t = threadIdx.x;
    const float* prow = poly + (size_t)r * D_DIM;
    const float* crow = cemb + (size_t)r * D_DIM;

    const float2 pv = *(const float2*)(prow + 2 * t);
    const float2 cv = *(const float2*)(crow + 2 * t);

    float ssp = pv.x * pv.x + pv.y * pv.y;
    float ssc = cv.x * cv.x + cv.y * cv.y;
    float dt  = pv.x * cv.x + pv.y * cv.y;

    #pragma unroll
    for (int m = 1; m < 64; m <<= 1) {
        ssp += __shfl_xor(ssp, m);
        ssc += __shfl_xor(ssc, m);
        dt  += __shfl_xor(dt,  m);
    }
    __shared__ float red[3][4];
    const int wave = t >> 6;
    if ((t & 63) == 0) { red[0][wave] = ssp; red[1][wave] = ssc; red[2][wave] = dt; }
    __syncthreads();
    ssp = red[0][0] + red[0][1] + red[0][2] + red[0][3];
    ssc = red[1][0] + red[1][1] + red[1][2] + red[1][3];
    dt  = red[2][0] + red[2][1] + red[2][2] + red[2][3];

    const float sp = 1.0f / fmaxf(sqrtf(ssp), 1e-12f);
    const float sc = 1.0f / fmaxf(sqrtf(ssc), 1e-12f);

    unsigned char* zp = Z + (size_t)r * D_DIM;
    unsigned char* zc = Z + (size_t)(r + B_ROWS) * D_DIM;
    const int pk = __builtin_amdgcn_cvt_pk_fp8_f32(pv.x * sp, pv.y * sp, 0, false);
    const int ck = __builtin_amdgcn_cvt_pk_fp8_f32(cv.x * sc, cv.y * sc, 0, false);
    *(unsigned short*)(zp + 2 * t) = (unsigned short)(pk & 0xffff);
    *(unsigned short*)(zc + 2 * t) = (unsigned short)(ck & 0xffff);

    if (t == 0) {
        pos[r] = dt * sp * sc;
        row_sum[2 * r]     = 0.0f;
        row_sum[2 * r + 1] = 0.0f;
        if (r == 0) *counter = 0u;
    }
}

// ---------------------------------------------------------------------------
// Kernel 2: symmetric sim = Z Z^T via mfma_scale_f32_16x16x128_f8f6f4 with
// UNIT scales (fp8 math at 2x the non-scaled rate; layout verified absmax
// 0.0 in rounds 1-4).
//
// Rounds 0-4 lesson: the LDS-staged lockstep loop is wave-starved: time is
// a pure function of resident waves (3 waves/SIMD -> 68.8 us; 2 -> ~95 us)
// regardless of MFMA rate, LDS instr count, or barrier count. Every wave
// parks at the stage -> vmcnt(0) -> barrier drain.
//
// This version DELETES the staging entirely. Z (4.2 MB) is L2-resident;
// each lane's fragment is 32 contiguous bytes at Z[row]*512 + quad*32 + k0
// -> two global dwordx4 loads, byte-identical v8i to the LDS path. No
// As/Bs, no K-loop barriers, no swizzle; LDS = reduction arrays only
// (~2 KB). #pragma unroll 1 keeps one K-step of fragments live (acc 64 +
// bfr 32 + afr 8 + addrs ~ 140 total -> 3 waves/SIMD, r0-class residency,
// zero lockstep; NO launch-bounds cap -- r2/r3 showed caps force spills).
// Extra L2 traffic vs staged (532 MB total) costs ~15 us at 34.5 TB/s.
// Epilogue / fence-free finalize byte-identical to round 0.
// ---------------------------------------------------------------------------
__global__ __launch_bounds__(256) void sim_kernel(
    const unsigned char* __restrict__ Z, float* __restrict__ row_sum,
    const float* __restrict__ pos, float* __restrict__ out,
    unsigned int* __restrict__ counter)
{
    __shared__ float rAcc[BM];
    __shared__ float cAcc[BN];
    __shared__ unsigned int lastFlag;

    // decode blockIdx.x -> (bi, bj), bi <= bj < 64; C(b) = b*(129-b)/2
    const int t0 = blockIdx.x;
    int bi = (int)((129.0f - sqrtf(16641.0f - 8.0f * (float)t0)) * 0.5f);
    #define CFN(b) ((b) * (129 - (b)) / 2)
    while (CFN(bi + 1) <= t0) ++bi;
    while (CFN(bi) > t0) --bi;
    const int bj = bi + (t0 - CFN(bi));
    #undef CFN

    const int ibase = bi * BM;
    const int jbase = bj * BN;
    const int tid   = threadIdx.x;

    const int wave = tid >> 6;
    const int lane = tid & 63;
    const int wi = (wave >> 1) * 64;
    const int wj = (wave & 1) * 64;
    const int quad = lane >> 4;
    const int c    = lane & 15;

    f32x4 acc[4][4] = {};

    // Per-lane fragment base addresses (computed once; K-loop adds k0).
    // Fragment for lane (c,quad), subtile t: bytes
    //   Z[(base + t*16 + c) * 512 + quad*32 + k0 .. +32]
    const unsigned char* aptr[4];
    const unsigned char* bptr[4];
    #pragma unroll
    for (int t = 0; t < 4; ++t) {
        aptr[t] = Z + (size_t)(ibase + wi + t * 16 + c) * D_DIM + quad * 32;
        bptr[t] = Z + (size_t)(jbase + wj + t * 16 + c) * D_DIM + quad * 32;
    }

    #pragma unroll 1
    for (int k0 = 0; k0 < D_DIM; k0 += BKB) {   // 4 iterations, rolled
        v8i bfr[4];
        #pragma unroll
        for (int tj = 0; tj < 4; ++tj) {
            const v4i lo = *(const v4i*)(bptr[tj] + k0);
            const v4i hi = *(const v4i*)(bptr[tj] + k0 + 16);
            bfr[tj] = __builtin_shufflevector(lo, hi, 0, 1, 2, 3, 4, 5, 6, 7);
        }
        #pragma unroll
        for (int ti = 0; ti < 4; ++ti) {
            const v4i lo = *(const v4i*)(aptr[ti] + k0);
            const v4i hi = *(const v4i*)(aptr[ti] + k0 + 16);
            const v8i afr = __builtin_shufflevector(lo, hi, 0, 1, 2, 3, 4, 5, 6, 7);
            #pragma unroll
            for (int tj = 0; tj < 4; ++tj)
                acc[ti][tj] = __builtin_amdgcn_mfma_scale_f32_16x16x128_f8f6f4(
                    afr, bfr[tj], acc[ti][tj],
                    0, 0,                 // cbsz / blgp: fp8 e4m3 both
                    0, 0x7f7f7f7f,        // opsel_a, scale_a = 1.0 (E8M0 127)
                    0, 0x7f7f7f7f);       // opsel_b, scale_b = 1.0
        }
    }

    // ---- Epilogue: strict-upper exp(sim/T), pre-reduced in LDS ----
    if (tid < BM) { rAcc[tid] = 0.0f; cAcc[tid] = 0.0f; }
    __syncthreads();

    const float K2 = 2.885390081777927f;  // 2*log2(e) = 1/(T*ln2)
    float col[4] = {0.0f, 0.0f, 0.0f, 0.0f};
    #pragma unroll
    for (int ti = 0; ti < 4; ++ti) {
        const int li = wi + ti * 16 + quad * 4;
        #pragma unroll
        for (int r = 0; r < 4; ++r) {
            const int gi = ibase + li + r;
            float v = 0.0f;
            #pragma unroll
            for (int tj = 0; tj < 4; ++tj) {
                const int gj = jbase + wj + tj * 16 + c;
                const float e = (gj > gi) ? exp2f(K2 * acc[ti][tj][r]) : 0.0f;
                v += e;
                col[tj] += e;
            }
            v += __shfl_xor(v, 1);
            v += __shfl_xor(v, 2);
            v += __shfl_xor(v, 4);
            v += __shfl_xor(v, 8);
            if (c == 0)
                atomicAdd(&rAcc[li + r], v);
        }
    }
    #pragma unroll
    for (int tj = 0; tj < 4; ++tj) {
        float w = col[tj];
        w += __shfl_xor(w, 16);
        w += __shfl_xor(w, 32);
        if (quad == 0)
            atomicAdd(&cAcc[wj + tj * 16 + c], w);
    }
    __syncthreads();

    if (tid < BM)
        atomicAdd(&row_sum[ibase + tid], rAcc[tid]);
    else
        atomicAdd(&row_sum[jbase + tid - BM], cAcc[tid - BM]);

    // ---- Completion count; last block computes the loss (fence-free) ----
    __syncthreads();   // barrier implies vmcnt(0): this block's atomics issued
    if (tid == 0) {
        unsigned int old = __hip_atomic_fetch_add(
            counter, 1u, __ATOMIC_RELAXED, __HIP_MEMORY_SCOPE_AGENT);
        lastFlag = (old == NPAIR - 1) ? 1u : 0u;
    }
    __syncthreads();
    if (lastFlag) {
        float accL = 0.0f, accP = 0.0f;
        for (int i = tid; i < N_ROWS; i += 256) {
            const float rs = __hip_atomic_load(
                &row_sum[i], __ATOMIC_RELAXED, __HIP_MEMORY_SCOPE_AGENT);
            accL += __logf(rs);
        }
        for (int r = tid; r < B_ROWS; r += 256)
            accP += pos[r];
        #pragma unroll
        for (int m = 1; m < 64; m <<= 1) {
            accL += __shfl_xor(accL, m);
            accP += __shfl_xor(accP, m);
        }
        if (lane == 0) { rAcc[wave] = accL; cAcc[wave] = accP; }
        __syncthreads();
        if (tid == 0) {
            float L = 0.0f, P = 0.0f;
            #pragma unroll
            for (int w = 0; w < 4; ++w) { L += rAcc[w]; P += cAcc[w]; }
            out[0] = (L - 4.0f * P) / (float)N_ROWS;
        }
    }
}

extern "C" void kernel_launch(void* const* d_in, const int* in_sizes, int n_in,
                              void* d_out, int out_size, void* d_ws, size_t ws_size,
                              hipStream_t stream) {
    const float* poly = (const float*)d_in[0];
    const float* cemb = (const float*)d_in[1];

    unsigned char* Z       = (unsigned char*)d_ws;
    float*         row_sum = (float*)((char*)d_ws + (size_t)N_ROWS * D_DIM);
    float*         pos     = row_sum + N_ROWS;
    unsigned int*  counter = (unsigned int*)(pos + B_ROWS);
    float*         out     = (float*)d_out;

    prep_kernel<<<B_ROWS, 256, 0, stream>>>(poly, cemb, Z, row_sum, pos, counter);
    sim_kernel<<<NPAIR, 256, 0, stream>>>(Z, row_sum, pos, out, counter);
}